// Round 14
// baseline (59.538 us; speedup 1.0000x reference)
//
#include <hip/hip_runtime.h>
#include <stdint.h>

// pooled[b,o] = x[b,:] . Wp[o,:] + biasp[o] + 0.25*(y[b,n0]+y[b,n0+1]+y[b,n0+64]+y[b,n0+65])
//   o = p*32+q, n0 = 128p+2q; Wp = 2x2-pooled W rows. out = pooled / mean(pooled).
// 3 dispatches: prep (x->bf16 + pool W/bias) -> gemm (128x128 tile, BK=32,
// 32KB LDS dbuf -> 2 blocks/CU, ONE barrier + ONE counted vmcnt(2) per K-tile,
// setprio MFMA, y interleaved lag-2 into acc, 1 output-q per tile) -> norm.

#define KDIM 1024
#define NP   1024
#define BM 128
#define BN 128
#define BK 32
#define NT 32
#define NBLK 512

typedef __bf16 bf16x8 __attribute__((ext_vector_type(8)));
typedef float f32x4 __attribute__((ext_vector_type(4)));
typedef _Float16 f16x4 __attribute__((ext_vector_type(4)));

__device__ __forceinline__ unsigned f2bf(float f) {
  union { float f; unsigned u; } v; v.f = f;
  unsigned r = v.u + 0x7fffu + ((v.u >> 16) & 1u);  // RNE
  return r >> 16;
}

__device__ __forceinline__ void gload_lds16(const void* g, void* l) {
  __builtin_amdgcn_global_load_lds(
      (const __attribute__((address_space(1))) void*)g,
      (__attribute__((address_space(3))) void*)l, 16, 0, 0);
}

// ---- kernel 1 (merged prep): x fp32->bf16 (blocks 0..4095), pool W+bias ----
__global__ void k_prep(const float* __restrict__ x, const float* __restrict__ W,
                       const float* __restrict__ bias,
                       unsigned short* __restrict__ xb, unsigned short* __restrict__ wp,
                       float* __restrict__ biasp) {
  int b = blockIdx.x;
  int t = threadIdx.x;
  if (b < 4096) {
    int i = b * 256 + t;  // 8 elems per thread
    const float4* x4 = (const float4*)x;
    float4 a = x4[i * 2], c = x4[i * 2 + 1];
    uint4 o;
    o.x = f2bf(a.x) | (f2bf(a.y) << 16);
    o.y = f2bf(a.z) | (f2bf(a.w) << 16);
    o.z = f2bf(c.x) | (f2bf(c.y) << 16);
    o.w = f2bf(c.z) | (f2bf(c.w) << 16);
    ((uint4*)xb)[i] = o;
  } else {
    int o = b - 4096;  // pooled feature index
    int r0 = ((o >> 5) << 7) + ((o & 31) << 1);
    const float4* W4 = (const float4*)W;
    float4 w0 = W4[(r0) * 256 + t];
    float4 w1 = W4[(r0 + 1) * 256 + t];
    float4 w2 = W4[(r0 + 64) * 256 + t];
    float4 w3 = W4[(r0 + 65) * 256 + t];
    float ax = 0.25f * (w0.x + w1.x + w2.x + w3.x);
    float ay = 0.25f * (w0.y + w1.y + w2.y + w3.y);
    float az = 0.25f * (w0.z + w1.z + w2.z + w3.z);
    float aw = 0.25f * (w0.w + w1.w + w2.w + w3.w);
    uint2 pk;
    pk.x = f2bf(ax) | (f2bf(ay) << 16);
    pk.y = f2bf(az) | (f2bf(aw) << 16);
    ((uint2*)wp)[o * 256 + t] = pk;
    if (t == 0)
      biasp[o] = 0.25f * (bias[r0] + bias[r0 + 1] + bias[r0 + 64] + bias[r0 + 65]);
  }
}

// ---- kernel 2: GEMM 128x128, BK=32, 2 blocks/CU, 1 barrier/vmcnt per tile ----
__global__ __launch_bounds__(512, 4) void k_gemm(
    const unsigned short* __restrict__ xb, const unsigned short* __restrict__ wp,
    const float* __restrict__ biasp, const float* __restrict__ y,
    float* __restrict__ out, _Float16* __restrict__ ph,
    float* __restrict__ partials, int use16) {
  // buf in {0,1}: A(buf)=smem+buf*16384 (8KB), B(buf)=+8192 (8KB). 32KB total.
  __shared__ char smem[32768];

  int bid = blockIdx.x;
  int wg = (bid & 7) * 64 + (bid >> 3);  // XCD swizzle, 512 = 8*64 bijective
  int bm0 = (wg >> 3) * BM;
  int bn0 = (wg & 7) * BN;

  int tid = threadIdx.x;
  int lane = tid & 63;
  int wid = tid >> 6;               // 0..7
  int wr = wid >> 1, wc = wid & 1;  // wave tile 32x64: rows wr*32, cols wc*64

  f32x4 acc[2][4];
#pragma unroll
  for (int i = 0; i < 2; i++)
#pragma unroll
    for (int j = 0; j < 4; j++) acc[i][j] = (f32x4)0.0f;

  // staging: rows are 64B (32 bf16); 512 thr x 16B = 8KB = full tile per call.
  // thread: row = tid>>2 (0..127), dest chunk = tid&3 (linear);
  // SOURCE chunk pre-swizzled: (tid&3)^((tid>>3)&3) = chunk ^ ((row>>1)&3).
  int srow = tid >> 2;
  int scol = (((tid & 3) ^ ((tid >> 3) & 3)) << 3);  // element offset (8 bf16)
  const unsigned short* aSrc = xb + (size_t)(bm0 + srow) * KDIM + scol;
  const unsigned short* bSrc = wp + (size_t)(bn0 + srow) * KDIM + scol;
  int ldsOff = wid * 1024;

  // read: row r (= mult16 + (lane&15)) byte base r*64 + 16*((lane>>4) ^
  // ((lane>>1)&3))  [= kchunk ^ s(row), s(row)=(row>>1)&3].
  int rbase = (lane & 15) * 64;
  int rchunk = (((lane >> 4) ^ ((lane >> 1) & 3)) << 4);

  // y: 32 outputs/thread, q = mi*16+ni*4+j (mi<2); tile t loads q=t (2 dwordx2),
  // consumed lag-2 into acc (2-slot rotating window).
  const float2* y2 = (const float2*)y;
  int r_l = (lane >> 4) * 4;
  int c_l = lane & 15;
  int yrb = bm0 + wr * 32 + r_l;
  int yb[4];
#pragma unroll
  for (int ni = 0; ni < 4; ++ni) {
    int col = bn0 + wc * 64 + ni * 16 + c_l;
    yb[ni] = ((col >> 5) << 6) + (col & 31);
  }
  float2 yin[2][2];

#define STAGE(buf, ks)                                                         \
  {                                                                            \
    int k0 = (ks) * BK;                                                        \
    char* ab = smem + (buf) * 16384 + ldsOff;                                  \
    char* bb = smem + (buf) * 16384 + 8192 + ldsOff;                           \
    gload_lds16(aSrc + k0, ab);                                                \
    gload_lds16(bSrc + k0, bb);                                                \
  }

#define YLOAD(slot, q)                                                         \
  {                                                                            \
    const float2* pp = y2 +                                                    \
        (size_t)(yrb + (((q) >> 4) * 16) + ((q) & 3)) * 2048 + yb[((q) >> 2) & 3]; \
    asm volatile("global_load_dwordx2 %0, %1, off"                             \
                 : "=v"(yin[slot][0]) : "v"(pp) : "memory");                   \
    asm volatile("global_load_dwordx2 %0, %1, off offset:256"                  \
                 : "=v"(yin[slot][1]) : "v"(pp) : "memory");                   \
  }
#define YCONS(slot, q)                                                         \
  {                                                                            \
    acc[(q) >> 4][((q) >> 2) & 3][(q) & 3] +=                                  \
        0.25f * ((yin[slot][0].x + yin[slot][0].y) +                           \
                 (yin[slot][1].x + yin[slot][1].y));                           \
  }

  // Per K-tile: issue order [A1, B1, Y2] = 4 events/tile. Open wait vmcnt(2)
  // allows only Y_{t-1} outstanding -> S_t and Y_{t-2} retired. Stage of
  // t+1 writes the buffer vacated at t-1 (safe after t's barrier).
#define TILE(t, WSTR)                                                          \
  {                                                                            \
    asm volatile(WSTR ::: "memory");                                           \
    __builtin_amdgcn_sched_barrier(0);                                         \
    __builtin_amdgcn_s_barrier();                                              \
    if ((t) >= 2) YCONS(((t) - 2) & 1, (t) - 2);                               \
    const char* Ab = smem + ((t) & 1) * 16384;                                 \
    const char* Bb = Ab + 8192;                                                \
    bf16x8 a0[2], b0[4];                                                       \
    _Pragma("unroll")                                                          \
    for (int mi = 0; mi < 2; ++mi)                                             \
      a0[mi] = *(const bf16x8*)(Ab + (wr * 32 + mi * 16) * 64 + rbase + rchunk); \
    _Pragma("unroll")                                                          \
    for (int ni = 0; ni < 4; ++ni)                                             \
      b0[ni] = *(const bf16x8*)(Bb + (wc * 64 + ni * 16) * 64 + rbase + rchunk); \
    if ((t) < NT - 1) STAGE(((t) + 1) & 1, (t) + 1);                           \
    YLOAD((t) & 1, t);                                                         \
    asm volatile("s_waitcnt lgkmcnt(0)" ::: "memory");                         \
    __builtin_amdgcn_sched_barrier(0);                                         \
    __builtin_amdgcn_s_setprio(1);                                             \
    _Pragma("unroll")                                                          \
    for (int mi = 0; mi < 2; ++mi)                                             \
      _Pragma("unroll")                                                        \
      for (int ni = 0; ni < 4; ++ni)                                           \
        acc[mi][ni] = __builtin_amdgcn_mfma_f32_16x16x32_bf16(                 \
            a0[mi], b0[ni], acc[mi][ni], 0, 0, 0);                             \
    __builtin_amdgcn_s_setprio(0);                                             \
  }

  STAGE(0, 0);
  TILE(0,  "s_waitcnt vmcnt(0)")
  TILE(1,  "s_waitcnt vmcnt(2)")
  TILE(2,  "s_waitcnt vmcnt(2)")
  TILE(3,  "s_waitcnt vmcnt(2)")
  TILE(4,  "s_waitcnt vmcnt(2)")
  TILE(5,  "s_waitcnt vmcnt(2)")
  TILE(6,  "s_waitcnt vmcnt(2)")
  TILE(7,  "s_waitcnt vmcnt(2)")
  TILE(8,  "s_waitcnt vmcnt(2)")
  TILE(9,  "s_waitcnt vmcnt(2)")
  TILE(10, "s_waitcnt vmcnt(2)")
  TILE(11, "s_waitcnt vmcnt(2)")
  TILE(12, "s_waitcnt vmcnt(2)")
  TILE(13, "s_waitcnt vmcnt(2)")
  TILE(14, "s_waitcnt vmcnt(2)")
  TILE(15, "s_waitcnt vmcnt(2)")
  TILE(16, "s_waitcnt vmcnt(2)")
  TILE(17, "s_waitcnt vmcnt(2)")
  TILE(18, "s_waitcnt vmcnt(2)")
  TILE(19, "s_waitcnt vmcnt(2)")
  TILE(20, "s_waitcnt vmcnt(2)")
  TILE(21, "s_waitcnt vmcnt(2)")
  TILE(22, "s_waitcnt vmcnt(2)")
  TILE(23, "s_waitcnt vmcnt(2)")
  TILE(24, "s_waitcnt vmcnt(2)")
  TILE(25, "s_waitcnt vmcnt(2)")
  TILE(26, "s_waitcnt vmcnt(2)")
  TILE(27, "s_waitcnt vmcnt(2)")
  TILE(28, "s_waitcnt vmcnt(2)")
  TILE(29, "s_waitcnt vmcnt(2)")
  TILE(30, "s_waitcnt vmcnt(2)")
  TILE(31, "s_waitcnt vmcnt(2)")

  asm volatile("s_waitcnt vmcnt(0)" ::: "memory");
  __builtin_amdgcn_sched_barrier(0);
  YCONS(0, 30);
  YCONS(1, 31);

  // epilogue: acc holds gemm + pooled y; add bias, store, block sum
  float tsum = 0.f;
  float bpv[4];
#pragma unroll
  for (int ni = 0; ni < 4; ++ni) bpv[ni] = biasp[bn0 + wc * 64 + ni * 16 + c_l];
#pragma unroll
  for (int mi = 0; mi < 2; ++mi) {
#pragma unroll
    for (int ni = 0; ni < 4; ++ni) {
      int col = bn0 + wc * 64 + ni * 16 + c_l;
#pragma unroll
      for (int j = 0; j < 4; ++j) {
        int row = bm0 + wr * 32 + mi * 16 + r_l + j;
        float val = acc[mi][ni][j] + bpv[ni];
        size_t o = (size_t)row * NP + col;
        if (use16) ph[o] = (_Float16)val;
        else out[o] = val;
        tsum += val;
      }
    }
  }
#pragma unroll
  for (int off = 32; off > 0; off >>= 1) tsum += __shfl_down(tsum, off);
  float* sm = (float*)smem;
  __syncthreads();
  if (lane == 0) sm[wid] = tsum;
  __syncthreads();
  if (tid == 0)
    partials[bid] = ((sm[0] + sm[1]) + (sm[2] + sm[3])) +
                    ((sm[4] + sm[5]) + (sm[6] + sm[7]));
}

// ---- kernel 3: redundant per-block reduce of 512 partials; scale to f32 out ----
__global__ void k_norm(float* __restrict__ out, const _Float16* __restrict__ ph,
                       const float* __restrict__ partials, int use16) {
  __shared__ float s[256];
  int t = threadIdx.x;
  s[t] = partials[t] + partials[t + 256];
  __syncthreads();
#pragma unroll
  for (int off = 128; off > 0; off >>= 1) {
    if (t < off) s[t] += s[t + off];
    __syncthreads();
  }
  float inv = 8388608.0f / s[0];  // (B*NP)/total
  int i = blockIdx.x * 256 + t;   // float4 index
  float4* o4 = (float4*)out;
  if (use16) {
    f16x4 hv = ((const f16x4*)ph)[i];
    float4 v;
    v.x = (float)hv[0] * inv;
    v.y = (float)hv[1] * inv;
    v.z = (float)hv[2] * inv;
    v.w = (float)hv[3] * inv;
    o4[i] = v;
  } else {
    float4 v = o4[i];
    v.x *= inv; v.y *= inv; v.z *= inv; v.w *= inv;
    o4[i] = v;
  }
}

extern "C" void kernel_launch(void* const* d_in, const int* in_sizes, int n_in,
                              void* d_out, int out_size, void* d_ws, size_t ws_size,
                              hipStream_t stream) {
  (void)in_sizes; (void)n_in; (void)out_size;
  const float* x = (const float*)d_in[0];
  const float* y = (const float*)d_in[1];
  const float* W = (const float*)d_in[2];
  const float* bias = (const float*)d_in[3];
  float* out = (float*)d_out;

  char* ws = (char*)d_ws;
  unsigned short* xb = (unsigned short*)(ws);                 // 16 MiB
  unsigned short* wp = (unsigned short*)(ws + 16777216);      // 2 MiB
  float* biasp = (float*)(ws + 16777216 + 2097152);           // 4 KiB
  float* partials = (float*)(ws + 16777216 + 2097152 + 4096); // 2 KiB
  _Float16* ph = (_Float16*)(ws + 20971520);                  // 16 MiB
  int use16 = (ws_size >= (size_t)20971520 + 16777216) ? 1 : 0;

  hipLaunchKernelGGL(k_prep, dim3(5120), dim3(256), 0, stream, x, W, bias, xb, wp, biasp);
  hipLaunchKernelGGL(k_gemm, dim3(NBLK), dim3(512), 0, stream, xb, wp, biasp, y, out, ph, partials, use16);
  hipLaunchKernelGGL(k_norm, dim3(8192), dim3(256), 0, stream, out, ph, partials, use16);
}